// Round 6
// baseline (494.997 us; speedup 1.0000x reference)
//
#include <hip/hip_runtime.h>
#include <hip/hip_bf16.h>

// Problem constants: B=64, C=256, H=W=28, N=784
#define BB   64
#define CC   256
#define NPIX 784
#define BNP  (BB * NPIX)   // 50176
#define SLOTS 128

// ---------------------------------------------------------------------------
// K1: masked pair cosine sims, straight from the ORIGINAL layouts (no
// transpose kernel). Block = (loss, b, 16 consecutive i), 1024 thr = 16
// waves, wave per i. y staged via full-64B-line reads (exact y fetch).
// z columns gathered with 16 scalar strided loads per lane (c = 4gl+q+64k,
// matching the y register layout); ||z_j||^2 computed inline in the same
// reduction tree. Mask math byte-identical to R2-R4 (absmax == 0).
// ---------------------------------------------------------------------------
__global__ __launch_bounds__(1024, 8) void pairs_k(
    const float* __restrict__ y1, const float* __restrict__ y2,
    const float* __restrict__ z1, const float* __restrict__ z2,
    const float* __restrict__ g1g, const float* __restrict__ g2g,
    double* __restrict__ acc) {
    __shared__ float  ylds[16 * 256];     // [i][c]
    __shared__ double shs[16];
    __shared__ int    shc[16];

    int tid  = threadIdx.x;
    int lane = tid & 63, wv = tid >> 6;
    int bx   = blockIdx.x;                   // [0, 6272)
    int loss = (bx >= 3136) ? 1 : 0;
    int rem  = bx - loss * 3136;
    int b    = rem / 49;
    int ig   = rem - b * 49;
    int i0   = 16 * ig;

    // stage y[b, :, i0..i0+15]: thread c<256 reads the full 64B line
    const float* Yg = (loss ? y2 : y1) + (size_t)b * CC * NPIX;
    if (tid < 256) {
        const float* row = Yg + (size_t)tid * NPIX + i0;
#pragma unroll
        for (int q = 0; q < 4; q++) {
            float4 v = *(const float4*)(row + 4 * q);
            ylds[(4 * q + 0) * 256 + tid] = v.x;
            ylds[(4 * q + 1) * 256 + tid] = v.y;
            ylds[(4 * q + 2) * 256 + tid] = v.z;
            ylds[(4 * q + 3) * 256 + tid] = v.w;
        }
    }

    const float* g1 = g1g + (size_t)b * 2 * NPIX;
    const float* g2 = g2g + (size_t)b * 2 * NPIX;
    int i = i0 + wv;
    float g1y = g1[i];
    float g1x = g1[NPIX + i];

    // bin = norm(grid[...,1,1] - grid[...,0,0])  (bit-exact chain)
    const float* gb = loss ? g2 : g1;
    float d0  = gb[29] - gb[0];
    float d1  = gb[NPIX + 29] - gb[NPIX];
    float bin = __fsqrt_rn(__fadd_rn(__fmul_rn(d0, d0), __fmul_rn(d1, d1)));

    // candidate box in grid2 index space (guard-widened superset; exact below)
    float t2y = g2[0], t2x = g2[NPIX];
    float s2y = g2[28] - g2[0];
    float s2x = g2[NPIX + 1] - g2[NPIX];
    float r  = 0.7f * bin * 1.0002f + 1e-4f;
    float cy = (g1y - t2y) / s2y;
    float cx = (g1x - t2x) / s2x;
    float ry = r / s2y + 0.05f;
    float rx = r / s2x + 0.05f;
    int jy0 = max(0,  (int)ceilf(cy - ry));
    int jy1 = min(27, (int)floorf(cy + ry));
    int jx0 = max(0,  (int)ceilf(cx - rx));
    int jx1 = min(27, (int)floorf(cx + rx));
    int dyr = jy1 - jy0, dxr = jx1 - jx0;

    int dyl = lane >> 2, dxl = lane & 3;
    bool pass = false;
    if (lane < 16 && dyl <= dyr && dxl <= dxr) {
        int jc = (jy0 + dyl) * 28 + jx0 + dxl;
        float dy = g1y - g2[jc];
        float dx = g1x - g2[NPIX + jc];
        float d  = __fsqrt_rn(__fadd_rn(__fmul_rn(dy, dy), __fmul_rn(dx, dx)));
        pass = (__fdiv_rn(d, bin) <= 0.7f);   // bit-exact mask decision
    }
    unsigned long long m = __ballot(pass);
    int cnt = __builtin_popcountll(m);

    __syncthreads();

    int gl = lane & 15, g = lane >> 4;
    const float4* Yr = (const float4*)(ylds + wv * 256);
    float4 ya = Yr[gl], yb = Yr[gl + 16], yc = Yr[gl + 32], yd = Yr[gl + 48];

    // na from registers (16-lane group reduce)
    float p = ya.x * ya.x;
    p = fmaf(ya.y, ya.y, p); p = fmaf(ya.z, ya.z, p); p = fmaf(ya.w, ya.w, p);
    p = fmaf(yb.x, yb.x, p); p = fmaf(yb.y, yb.y, p); p = fmaf(yb.z, yb.z, p);
    p = fmaf(yb.w, yb.w, p);
    p = fmaf(yc.x, yc.x, p); p = fmaf(yc.y, yc.y, p); p = fmaf(yc.z, yc.z, p);
    p = fmaf(yc.w, yc.w, p);
    p = fmaf(yd.x, yd.x, p); p = fmaf(yd.y, yd.y, p); p = fmaf(yd.z, yd.z, p);
    p = fmaf(yd.w, yd.w, p);
#pragma unroll
    for (int off = 1; off < 16; off <<= 1) p += __shfl_xor(p, off);
    float na = __fsqrt_rn(p);

    // z in ORIGINAL [C,N] layout: column j = 16 strided scalars per lane
    const float* Zg = (loss ? z1 : z2) + (size_t)b * CC * NPIX;

    double ssum = 0.0;
#pragma unroll
    for (int rr = 0; rr < 4; rr++) {
        int mr = (int)((m >> (4 * rr)) & 15ull);
        if (!mr) continue;
        int s   = 4 * rr + g;                 // this group's slot
        bool val = (mr >> g) & 1;
        int j = val ? ((jy0 + (s >> 2)) * 28 + jx0 + (s & 3))
                    : (jy0 * 28 + jx0);
        const float* Zc = Zg + j;
        int cb = 4 * gl;
        float4 za, zb_, zc, zd;
        za.x  = Zc[(size_t)(cb + 0) * NPIX];
        za.y  = Zc[(size_t)(cb + 1) * NPIX];
        za.z  = Zc[(size_t)(cb + 2) * NPIX];
        za.w  = Zc[(size_t)(cb + 3) * NPIX];
        zb_.x = Zc[(size_t)(cb + 64) * NPIX];
        zb_.y = Zc[(size_t)(cb + 65) * NPIX];
        zb_.z = Zc[(size_t)(cb + 66) * NPIX];
        zb_.w = Zc[(size_t)(cb + 67) * NPIX];
        zc.x  = Zc[(size_t)(cb + 128) * NPIX];
        zc.y  = Zc[(size_t)(cb + 129) * NPIX];
        zc.z  = Zc[(size_t)(cb + 130) * NPIX];
        zc.w  = Zc[(size_t)(cb + 131) * NPIX];
        zd.x  = Zc[(size_t)(cb + 192) * NPIX];
        zd.y  = Zc[(size_t)(cb + 193) * NPIX];
        zd.z  = Zc[(size_t)(cb + 194) * NPIX];
        zd.w  = Zc[(size_t)(cb + 195) * NPIX];

        float dp = ya.x * za.x;
        float zz = za.x * za.x;
        dp = fmaf(ya.y, za.y, dp);  zz = fmaf(za.y, za.y, zz);
        dp = fmaf(ya.z, za.z, dp);  zz = fmaf(za.z, za.z, zz);
        dp = fmaf(ya.w, za.w, dp);  zz = fmaf(za.w, za.w, zz);
        dp = fmaf(yb.x, zb_.x, dp); zz = fmaf(zb_.x, zb_.x, zz);
        dp = fmaf(yb.y, zb_.y, dp); zz = fmaf(zb_.y, zb_.y, zz);
        dp = fmaf(yb.z, zb_.z, dp); zz = fmaf(zb_.z, zb_.z, zz);
        dp = fmaf(yb.w, zb_.w, dp); zz = fmaf(zb_.w, zb_.w, zz);
        dp = fmaf(yc.x, zc.x, dp);  zz = fmaf(zc.x, zc.x, zz);
        dp = fmaf(yc.y, zc.y, dp);  zz = fmaf(zc.y, zc.y, zz);
        dp = fmaf(yc.z, zc.z, dp);  zz = fmaf(zc.z, zc.z, zz);
        dp = fmaf(yc.w, zc.w, dp);  zz = fmaf(zc.w, zc.w, zz);
        dp = fmaf(yd.x, zd.x, dp);  zz = fmaf(zd.x, zd.x, zz);
        dp = fmaf(yd.y, zd.y, dp);  zz = fmaf(zd.y, zd.y, zz);
        dp = fmaf(yd.z, zd.z, dp);  zz = fmaf(zd.z, zd.z, zz);
        dp = fmaf(yd.w, zd.w, dp);  zz = fmaf(zd.w, zd.w, zz);
#pragma unroll
        for (int off = 1; off < 16; off <<= 1) {
            dp += __shfl_xor(dp, off);
            zz += __shfl_xor(zz, off);
        }
        float den = fmaxf(na * __fsqrt_rn(zz), 1e-8f);
        float sim = __fdividef(dp, den);
        if (val) ssum += (double)sim;
    }
    // combine the 4 groups (lanes within a group hold identical ssum)
    ssum += __shfl_xor(ssum, 16);
    ssum += __shfl_xor(ssum, 32);

    if (lane == 0) { shs[wv] = ssum; shc[wv] = cnt; }
    __syncthreads();
    if (tid == 0) {
        double s = 0.0; int c = 0;
#pragma unroll
        for (int k = 0; k < 16; k++) { s += shs[k]; c += shc[k]; }
        double* slot = acc + (size_t)(bx & (SLOTS - 1)) * 4;
        atomicAdd(&slot[loss * 2],     s);
        atomicAdd(&slot[loss * 2 + 1], (double)c);
    }
}

// ---------------------------------------------------------------------------
// K2: finalize  loss = -(S0/M0 + S1/M1)  (reduce the 128 slots)
// ---------------------------------------------------------------------------
__global__ void fin_k(const double* __restrict__ acc, float* __restrict__ out) {
    int lane = threadIdx.x;   // 64 threads
    double s0 = 0, m0 = 0, s1 = 0, m1 = 0;
    for (int s = lane; s < SLOTS; s += 64) {
        const double* p = acc + (size_t)s * 4;
        s0 += p[0]; m0 += p[1]; s1 += p[2]; m1 += p[3];
    }
#pragma unroll
    for (int off = 32; off; off >>= 1) {
        s0 += __shfl_xor(s0, off); m0 += __shfl_xor(m0, off);
        s1 += __shfl_xor(s1, off); m1 += __shfl_xor(m1, off);
    }
    if (lane == 0) out[0] = (float)(-(s0 / m0 + s1 / m1));
}

extern "C" void kernel_launch(void* const* d_in, const int* in_sizes, int n_in,
                              void* d_out, int out_size, void* d_ws, size_t ws_size,
                              hipStream_t stream) {
    const float* y1 = (const float*)d_in[0];
    const float* y2 = (const float*)d_in[1];
    const float* z1 = (const float*)d_in[2];
    const float* z2 = (const float*)d_in[3];
    const float* g1 = (const float*)d_in[4];
    const float* g2 = (const float*)d_in[5];
    float* out = (float*)d_out;

    double* acc = (double*)d_ws;                       // SLOTS*4 doubles = 4 KB
    hipMemsetAsync(acc, 0, SLOTS * 4 * sizeof(double), stream);

    // pairs: 2 losses * 64 b * 49 i-groups = 6272 blocks x 1024 threads
    pairs_k<<<6272, 1024, 0, stream>>>(y1, y2, z1, z2, g1, g2, acc);

    fin_k<<<1, 64, 0, stream>>>(acc, out);
}